// Round 18
// baseline (6801.872 us; speedup 1.0000x reference)
//
#include <hip/hip_runtime.h>
#include <hip/hip_bf16.h>

// ---------------------------------------------------------------------------
// CharRNN: emb -> 4x conv1d(SAME) -> concat -> GRU(256) last state.
//
// xw[b,t,:] = (beff+brec folded into MFMA acc) + sum_d EmbW[d][X[b,t+d-2]][:]
//
// R18: rounds 9-17 proved cross-block h-exchange has a ~2-4us/step uncachable
// cross-XCD latency floor. Eliminate it: ONE block owns a whole group
// (16 batch rows x all 768 cols); Wh is NOT register-persistent -- it is
// RE-STREAMED from the XCD-local L2 every step (393KB @ ~4TB/s ~= 130cy,
// hidden under the 930cy MFMA phase). h lives purely in LDS (split-bf16
// hi/lo, parity dbuf). 8 blocks total, zero inter-block communication,
// no atomics/spins/marks -> deterministic by construction.
// Numerics identical to R14 (split-bf16 h, f32 tables): absmax 9.8e-4.
// ---------------------------------------------------------------------------

typedef float f32x4 __attribute__((ext_vector_type(4)));
typedef short s16x8 __attribute__((ext_vector_type(8)));
typedef unsigned short u16;
typedef unsigned int   u32;

// ws byte offsets
#define OFF_WC    0u         // f32  [5][64][768]
#define OFF_EMBW  983040u    // f32  [5][128][768]
#define OFF_BEFF  2949120u   // f32  [768]
#define OFF_WHP   2952192u   // bf16 [768][256] (Wh^T)
#define OFF_MODE  3345408u   // int
#define WS_NEED   3345472u

__device__ __forceinline__ float bf2f(u16 v){
  unsigned u = ((unsigned)v) << 16; return __builtin_bit_cast(float, u);
}
__device__ __forceinline__ u16 f2bf(float f){
  unsigned u = __builtin_bit_cast(unsigned, f);
  unsigned r = u + 0x7FFFu + ((u >> 16) & 1u);
  return (u16)(r >> 16);
}
__device__ __forceinline__ float ldv(const void* p, int i, int m){
  return m ? ((const float*)p)[i] : bf2f(((const u16*)p)[i]);
}

// ---- probe: detect storage dtype of emb_table ----
__global__ void k_probe(const void* __restrict__ emb, char* ws){
  const u16* w = (const u16*)emb;
  const int ln = threadIdx.x;
  bool bad = false;
  for (int j = 0; j < 8; ++j){
    u16 v = w[ln*8 + j];
    if (((v >> 7) & 0xFF) >= 0x86) bad = true;
  }
  unsigned long long m = __ballot(bad);
  if (ln == 0) *(int*)(ws + OFF_MODE) = (__popcll(m) > 4) ? 1 : 0;
}

// ---- Wc[d][e][j] = sum_br sum_c w_br[d-2+pad][e][c] * Wx[off_br+c][j] ----
__global__ void k_wc(const void* __restrict__ w2, const void* __restrict__ w3,
                     const void* __restrict__ w4, const void* __restrict__ w5,
                     const void* __restrict__ Wx, char* ws){
  const int md = *(const int*)(ws + OFF_MODE);
  const int d = blockIdx.x >> 6;
  const int e = blockIdx.x & 63;
  const int j0 = threadIdx.x;
  const void* wv[4] = {w2,w3,w4,w5};
  const int Kk[4] = {2,3,4,5}, pd[4] = {0,1,1,2};
  float a0=0.f, a1=0.f, a2=0.f;
  for (int br=0; br<4; ++br){
    int k = d - 2 + pd[br];
    if (k < 0 || k >= Kk[br]) continue;
    const int wbase  = (k*64 + e)*128;
    const int wxbase = (br*128)*768;
    for (int c=0; c<128; ++c){
      float wcv = ldv(wv[br], wbase + c, md);
      a0 += wcv * ldv(Wx, wxbase + c*768 + j0      , md);
      a1 += wcv * ldv(Wx, wxbase + c*768 + j0 + 256, md);
      a2 += wcv * ldv(Wx, wxbase + c*768 + j0 + 512, md);
    }
  }
  float* o = (float*)(ws + OFF_WC) + (d*64 + e)*768;
  o[j0] = a0; o[j0+256] = a1; o[j0+512] = a2;
}

// ---- beff[j] = b_in[j] + sum_br sum_c b_br[c]*Wx[off+c][j] ----
__global__ void k_beff(const void* __restrict__ b2, const void* __restrict__ b3,
                       const void* __restrict__ b4, const void* __restrict__ b5,
                       const void* __restrict__ Wx, const void* __restrict__ bin,
                       char* ws){
  const int md = *(const int*)(ws + OFF_MODE);
  int j = blockIdx.x*256 + threadIdx.x;
  if (j >= 768) return;
  const void* bv[4] = {b2,b3,b4,b5};
  float acc = ldv(bin, j, md);
  for (int br=0; br<4; ++br)
    for (int c=0; c<128; ++c)
      acc += ldv(bv[br], c, md) * ldv(Wx, (br*128 + c)*768 + j, md);
  ((float*)(ws + OFF_BEFF))[j] = acc;
}

// ---- EmbW[d][ch][j] = sum_e emb[ch][e] * Wc[d][e][j]  (f32 out) ----
__global__ void k_embw(const void* __restrict__ emb, char* ws){
  const int md = *(const int*)(ws + OFF_MODE);
  const int d = blockIdx.x >> 7, ch = blockIdx.x & 127;
  const float* wc = (const float*)(ws + OFF_WC) + d*64*768;
  float* ew = (float*)(ws + OFF_EMBW) + (size_t)(d*128 + ch)*768;
  const int j0 = threadIdx.x;
  float a0=0.f, a1=0.f, a2=0.f;
  for (int e=0; e<64; ++e){
    float ev = ldv(emb, ch*64 + e, md);
    a0 += ev*wc[e*768 + j0      ];
    a1 += ev*wc[e*768 + j0 + 256];
    a2 += ev*wc[e*768 + j0 + 512];
  }
  ew[j0] = a0; ew[j0+256] = a1; ew[j0+512] = a2;
}

// ---- whp[j][k] = Wh[k][j]  (bf16 out) ----
__global__ void k_whp(const void* __restrict__ Wh, char* ws){
  const int md = *(const int*)(ws + OFF_MODE);
  const int j = blockIdx.x, k = threadIdx.x;
  ((u16*)(ws + OFF_WHP))[j*256 + k] = f2bf(ldv(Wh, k*768 + j, md));
}

// ---- GRU: 8 blocks (one group of 16 batch rows each) x 512 thr / 8 waves ----
__launch_bounds__(512, 1)
__global__ void k_gru(const int* __restrict__ X, const void* __restrict__ brec,
                      const char* __restrict__ ws, void* __restrict__ outv){
  const int tid = threadIdx.x;
  const int w   = tid >> 6, ln = tid & 63;
  const int l15 = ln & 15, l4 = ln >> 4;
  const int g = blockIdx.x;

  const int md = *(const int*)(ws + OFF_MODE);
  const float* embw  = (const float*)(ws + OFF_EMBW);
  const float* beffp = (const float*)(ws + OFF_BEFF);
  const u16*   whp   = (const u16*)(ws + OFF_WHP);

  __shared__ u16   hstage[2][2][16][264];  // [par][hi/lo][row][256+8pad] 33.8KB
  __shared__ float hwlds[16][772];         // [row][768+4pad]             49.4KB

  // ---- MFMA role: wave w owns cols [w*96, w*96+96) (6 tiles), full K ----
  const int colbase = w*96;
  float bfc[6];                    // folded bias: brec[col] + beff[col]
  const u16* bbase[6];             // B-frag base: whp + col*256 + l4*8
  #pragma unroll
  for (int t=0; t<6; ++t){
    const int col = colbase + t*16 + l15;
    bfc[t] = ldv(brec, col, md) + beffp[col];
    bbase[t] = whp + col*256 + l4*8;
  }

  // ---- gate role: thread owns (row=tid&15, cols C*8..C*8+8 of each gate) ----
  const int grow = tid & 15, C = tid >> 4;
  const int xrow = (g*16 + grow)*512;

  // zero h parity-0 planes (h(0) = 0)
  {
    u32* hz = (u32*)&hstage[0][0][0][0];
    for (int i = tid; i < 4224; i += 512) hz[i] = 0u;
  }

  // xw(0): per-thread gather into registers (taps t = d-2)
  f32x4 xwv[3][2];
  #pragma unroll
  for (int gg=0; gg<3; ++gg){ xwv[gg][0] = (f32x4){0,0,0,0}; xwv[gg][1] = (f32x4){0,0,0,0}; }
  #pragma unroll
  for (int d=0; d<5; ++d){
    const int t = d - 2;
    if ((unsigned)t < 512u){
      const int ch = X[xrow + t] & 127;
      const float* tb = embw + (size_t)(d*128 + ch)*768 + C*8;
      #pragma unroll
      for (int gg=0; gg<3; ++gg){
        xwv[gg][0] += *(const f32x4*)(tb + gg*256);
        xwv[gg][1] += *(const f32x4*)(tb + gg*256 + 4);
      }
    }
  }
  float hprev[8] = {0.f,0.f,0.f,0.f,0.f,0.f,0.f,0.f};
  __syncthreads();

  for (int s = 0; s < 512; ++s){
    const int par = s & 1;

    // P1) hw = (h_hi + h_lo) @ Wh + (brec+beff): 96 MFMAs/wave,
    //     B streamed from L2 (whp is XCD-L2-resident), A from LDS.
    f32x4 acc[6];
    #pragma unroll
    for (int t=0; t<6; ++t) acc[t] = (f32x4){bfc[t], bfc[t], bfc[t], bfc[t]};
    #pragma unroll
    for (int q=0; q<8; ++q){
      const s16x8 ahi = *(const s16x8*)&hstage[par][0][l15][q*32 + l4*8];
      const s16x8 alo = *(const s16x8*)&hstage[par][1][l15][q*32 + l4*8];
      #pragma unroll
      for (int t=0; t<6; ++t){
        const s16x8 bf = *(const s16x8*)(bbase[t] + q*32);
        acc[t] = __builtin_amdgcn_mfma_f32_16x16x32_bf16(ahi, bf, acc[t], 0,0,0);
        acc[t] = __builtin_amdgcn_mfma_f32_16x16x32_bf16(alo, bf, acc[t], 0,0,0);
      }
    }
    // publish hw to LDS: D row = l4*4+p, col = colbase + t*16 + l15
    #pragma unroll
    for (int t=0; t<6; ++t){
      const int col = colbase + t*16 + l15;
      #pragma unroll
      for (int p=0; p<4; ++p)
        hwlds[l4*4+p][col] = acc[t][p];
    }

    // P2) gather xw(s+1) into regs (acc now dead; loads fly over barrier+gates)
    f32x4 nx[3][2];
    #pragma unroll
    for (int gg=0; gg<3; ++gg){ nx[gg][0] = (f32x4){0,0,0,0}; nx[gg][1] = (f32x4){0,0,0,0}; }
    if (s < 511){
      #pragma unroll
      for (int d=0; d<5; ++d){
        const int t = s - 1 + d;
        if ((unsigned)t < 512u){
          const int ch = X[xrow + t] & 127;
          const float* tb = embw + (size_t)(d*128 + ch)*768 + C*8;
          #pragma unroll
          for (int gg=0; gg<3; ++gg){
            nx[gg][0] += *(const f32x4*)(tb + gg*256);
            nx[gg][1] += *(const f32x4*)(tb + gg*256 + 4);
          }
        }
      }
    }
    __syncthreads();                          // barB: hwlds ready

    // P3) gates: thread unit (grow, C*8+j), j=0..7 (biases already in hw)
    f32x4 hv[3][2];
    #pragma unroll
    for (int gg=0; gg<3; ++gg){
      hv[gg][0] = *(const f32x4*)&hwlds[grow][gg*256 + C*8];
      hv[gg][1] = *(const f32x4*)&hwlds[grow][gg*256 + C*8 + 4];
    }
    float hn[8];
    #pragma unroll
    for (int hh2=0; hh2<2; ++hh2){
      #pragma unroll
      for (int e=0; e<4; ++e){
        const int j = hh2*4 + e;
        const float z  = 1.f/(1.f + __expf(-(xwv[0][hh2][e] + hv[0][hh2][e])));
        const float r  = 1.f/(1.f + __expf(-(xwv[1][hh2][e] + hv[1][hh2][e])));
        const float pre = xwv[2][hh2][e] + r*hv[2][hh2][e];
        const float e2  = __expf(-2.f*fabsf(pre));
        const float th  = __builtin_copysignf((1.f - e2)/(1.f + e2), pre);
        hn[j] = z*hprev[j] + (1.f - z)*th;
        hprev[j] = hn[j];
      }
    }

    // P4) publish h(s+1) (split-bf16 hi/lo) to parity par^1, or final output
    if (s == 511){
      const int i0 = (g*16 + grow)*256 + C*8;
      if (md){
        #pragma unroll
        for (int j=0; j<8; ++j) ((float*)outv)[i0 + j] = hn[j];
      } else {
        s16x8 o8;
        #pragma unroll
        for (int j=0; j<8; ++j) o8[j] = (short)f2bf(hn[j]);
        *(s16x8*)&((u16*)outv)[i0] = o8;
      }
    } else {
      s16x8 hi8, lo8;
      #pragma unroll
      for (int j=0; j<8; ++j){
        const u16 bh = f2bf(hn[j]);
        hi8[j] = (short)bh;
        lo8[j] = (short)f2bf(hn[j] - bf2f(bh));
      }
      *(s16x8*)&hstage[par^1][0][grow][C*8] = hi8;
      *(s16x8*)&hstage[par^1][1][grow][C*8] = lo8;
      #pragma unroll
      for (int gg=0; gg<3; ++gg){ xwv[gg][0] = nx[gg][0]; xwv[gg][1] = nx[gg][1]; }
    }
    __syncthreads();                          // end: hstage(par^1) ready, hwlds free
  }
}

extern "C" void kernel_launch(void* const* d_in, const int* in_sizes, int n_in,
                              void* d_out, int out_size, void* d_ws, size_t ws_size,
                              hipStream_t stream){
  const int* X = (const int*)d_in[0];
  char* ws = (char*)d_ws;
  if (ws_size < WS_NEED) return;

  k_probe<<<  1,  64, 0, stream>>>(d_in[1], ws);
  k_wc   <<<320, 256, 0, stream>>>(d_in[2], d_in[4], d_in[6], d_in[8], d_in[10], ws);
  k_beff <<<  3, 256, 0, stream>>>(d_in[3], d_in[5], d_in[7], d_in[9], d_in[10], d_in[12], ws);
  k_embw <<<640, 256, 0, stream>>>(d_in[1], ws);
  k_whp  <<<768, 256, 0, stream>>>(d_in[11], ws);
  k_gru  <<<  8, 512, 0, stream>>>(X, d_in[13], ws, d_out);
}